// Round 1
// baseline (4969.818 us; speedup 1.0000x reference)
//
#include <hip/hip_runtime.h>
#include <math.h>

typedef unsigned short u16;
typedef u16 u16x8 __attribute__((ext_vector_type(8)));
typedef u16 u16x4 __attribute__((ext_vector_type(4)));
typedef short short8 __attribute__((ext_vector_type(8)));
typedef float f32x4 __attribute__((ext_vector_type(4)));

#define NE 768
#define NH 12
#define NL 12
#define NV 50257
#define HD 64
#define DFF 3072
#define NB 2
#define SL 1024
#define TT 2048   // NB*SL tokens

static __device__ __forceinline__ float bf2f(u16 u){
  unsigned int x = ((unsigned int)u) << 16;
  float f; __builtin_memcpy(&f, &x, 4); return f;
}
static __device__ __forceinline__ u16 f2bf(float f){
  unsigned int x; __builtin_memcpy(&x, &f, 4);
  x = (x + 0x7FFFu + ((x >> 16) & 1u)) >> 16;
  return (u16)x;
}

// ---------------- fp32 -> bf16 convert (vectorized) ----------------
__global__ void k_cvt4(const float4* __restrict__ in, u16x4* __restrict__ out, long n4){
  long i = (long)blockIdx.x * blockDim.x + threadIdx.x;
  long st = (long)gridDim.x * blockDim.x;
  for (; i < n4; i += st){
    float4 v = in[i];
    u16x4 o = { f2bf(v.x), f2bf(v.y), f2bf(v.z), f2bf(v.w) };
    out[i] = o;
  }
}

// ------------- fp32 [K][N] -> bf16 [N][K] transpose-convert -------------
__global__ __launch_bounds__(256) void k_transpose_cvt(const float* __restrict__ in,
    u16* __restrict__ out, int K, int N){
  __shared__ u16 tile[32][33];
  int n0 = blockIdx.x * 32, k0 = blockIdx.y * 32;
#pragma unroll
  for (int i = 0; i < 4; ++i){
    int e = threadIdx.x + i * 256;
    int r = e >> 5, c = e & 31;          // r: k, c: n
    int k = k0 + r, n = n0 + c;
    float v = (k < K && n < N) ? in[(long)k * N + n] : 0.f;
    tile[r][c] = f2bf(v);
  }
  __syncthreads();
#pragma unroll
  for (int i = 0; i < 4; ++i){
    int e = threadIdx.x + i * 256;
    int r = e >> 5, c = e & 31;          // r: n, c: k
    int n = n0 + r, k = k0 + c;
    if (n < N && k < K) out[(long)n * K + k] = tile[c][r];
  }
}

// ---------------- LayerNorm: f32 [TT][768] -> bf16 ----------------
__global__ __launch_bounds__(256) void k_layernorm(const float* __restrict__ x,
    const float* __restrict__ g, const float* __restrict__ b, u16* __restrict__ out){
  int row = blockIdx.x;
  const float* xr = x + (long)row * NE;
  int t = threadIdx.x;
  float v[3];
  v[0] = xr[t]; v[1] = xr[t + 256]; v[2] = xr[t + 512];
  float s = v[0] + v[1] + v[2];
  float sq = v[0]*v[0] + v[1]*v[1] + v[2]*v[2];
  __shared__ float red[8];
#pragma unroll
  for (int o = 32; o; o >>= 1){ s += __shfl_xor(s, o); sq += __shfl_xor(sq, o); }
  int wid = t >> 6, lane = t & 63;
  if (!lane){ red[wid] = s; red[4 + wid] = sq; }
  __syncthreads();
  s  = red[0] + red[1] + red[2] + red[3];
  sq = red[4] + red[5] + red[6] + red[7];
  float mean = s * (1.f / NE);
  float var  = sq * (1.f / NE) - mean * mean;
  float rs = rsqrtf(var + 1e-5f);
  u16* orow = out + (long)row * NE;
#pragma unroll
  for (int i = 0; i < 3; ++i){
    int c = t + i * 256;
    orow[c] = f2bf((v[i] - mean) * rs * g[c] + b[c]);
  }
}

// -------- build V^T: qkv bf16 -> vt[bh][d][kk] --------
__global__ __launch_bounds__(256) void k_build_vt(const u16* __restrict__ qkv,
    u16* __restrict__ vt){
  int z = blockIdx.x;                    // b*12 + h
  int b = z / NH, h = z % NH;
  int kk0 = blockIdx.y * 32;
  __shared__ u16 tile[32][66];
  const u16* src = qkv + ((long)(b * SL + kk0)) * (3 * NE) + 2 * NE + h * HD;
#pragma unroll
  for (int i = 0; i < 8; ++i){
    int e = threadIdx.x + i * 256;
    int kk = e >> 6, d = e & 63;
    tile[kk][d] = src[(long)kk * (3 * NE) + d];
  }
  __syncthreads();
  u16* dst = vt + (long)z * HD * SL + kk0;
#pragma unroll
  for (int i = 0; i < 8; ++i){
    int e = threadIdx.x + i * 256;
    int d = e >> 5, kk = e & 31;
    dst[(long)d * SL + kk] = tile[kk][d];
  }
}

// -------- causal softmax: scores f32 [24*SL][SL] -> probs bf16 --------
__global__ __launch_bounds__(256) void k_softmax(const float* __restrict__ sc,
    u16* __restrict__ pr){
  long rowbase = (long)blockIdx.x * SL;
  int q = blockIdx.x & (SL - 1);
  int t = threadIdx.x, wid = t >> 6, lane = t & 63;
  __shared__ float red[4];
  float vals[4];
  float mx = -1e30f;
#pragma unroll
  for (int i = 0; i < 4; ++i){
    int c = t + i * 256;
    float v = sc[rowbase + c] * 0.125f;
    if (c > q) v = -1e30f;
    vals[i] = v;
    mx = fmaxf(mx, v);
  }
#pragma unroll
  for (int o = 32; o; o >>= 1) mx = fmaxf(mx, __shfl_xor(mx, o));
  if (!lane) red[wid] = mx;
  __syncthreads();
  mx = fmaxf(fmaxf(red[0], red[1]), fmaxf(red[2], red[3]));
  __syncthreads();
  float sum = 0.f;
#pragma unroll
  for (int i = 0; i < 4; ++i){
    float e = __expf(vals[i] - mx);
    vals[i] = e; sum += e;
  }
#pragma unroll
  for (int o = 32; o; o >>= 1) sum += __shfl_xor(sum, o);
  if (!lane) red[wid] = sum;
  __syncthreads();
  sum = red[0] + red[1] + red[2] + red[3];
  float inv = 1.f / sum;
#pragma unroll
  for (int i = 0; i < 4; ++i){
    int c = t + i * 256;
    pr[rowbase + c] = f2bf(vals[i] * inv);
  }
}

// ---------------- generic bf16 MFMA GEMM, B^T layout ----------------
// C[M,N] = A[M,K] * B^T[N,K]  (+bias)(+res)(gelu), optional batch via grid.z
// modes: 0 bf16 raw, 1 bf16 +bias, 2 bf16 +bias +gelu(erf), 3 f32 raw, 4 f32 +bias +res
struct GemmP {
  const u16* A; const u16* B; void* C;
  const float* bias; const float* res;
  int M, N, K, lda, ldb, ldc, mode, H;
  long sAb, sAh, sBb, sBh, sCb, sCh;
};

__global__ __launch_bounds__(256) void k_gemm_bt(GemmP p){
  __shared__ u16 As[128][40];
  __shared__ u16 Bs[128][40];
  long offA = 0, offB = 0, offC = 0;
  if (p.H){
    int z = blockIdx.z, zb = z / p.H, zh = z % p.H;
    offA = (long)zb * p.sAb + (long)zh * p.sAh;
    offB = (long)zb * p.sBb + (long)zh * p.sBh;
    offC = (long)zb * p.sCb + (long)zh * p.sCh;
  }
  const u16* A = p.A + offA;
  const u16* B = p.B + offB;
  const int m0 = blockIdx.x * 128, n0 = blockIdx.y * 128;
  const int t = threadIdx.x, lane = t & 63, wid = t >> 6;
  const int wm = (wid >> 1) * 64, wn = (wid & 1) * 64;
  const int lr = lane & 15, lk = lane >> 4;
  f32x4 acc[4][4] = {};
  for (int k0 = 0; k0 < p.K; k0 += 32){
#pragma unroll
    for (int i = 0; i < 2; ++i){
      int e = t + i * 256, row = e >> 2, ch = e & 3;
      u16x8 v = *(const u16x8*)(A + (long)(m0 + row) * p.lda + (k0 + ch * 8));
      *(u16x8*)&As[row][ch * 8] = v;
    }
#pragma unroll
    for (int i = 0; i < 2; ++i){
      int e = t + i * 256, row = e >> 2, ch = e & 3;
      u16x8 v = {0,0,0,0,0,0,0,0};
      if (n0 + row < p.N)
        v = *(const u16x8*)(B + (long)(n0 + row) * p.ldb + (k0 + ch * 8));
      *(u16x8*)&Bs[row][ch * 8] = v;
    }
    __syncthreads();
    short8 af[4], bfr[4];
#pragma unroll
    for (int i = 0; i < 4; ++i) af[i]  = *(const short8*)&As[wm + i * 16 + lr][lk * 8];
#pragma unroll
    for (int j = 0; j < 4; ++j) bfr[j] = *(const short8*)&Bs[wn + j * 16 + lr][lk * 8];
#pragma unroll
    for (int i = 0; i < 4; ++i)
#pragma unroll
      for (int j = 0; j < 4; ++j)
        acc[i][j] = __builtin_amdgcn_mfma_f32_16x16x32_bf16(af[i], bfr[j], acc[i][j], 0, 0, 0);
    __syncthreads();
  }
#pragma unroll
  for (int i = 0; i < 4; ++i){
#pragma unroll
    for (int r = 0; r < 4; ++r){
      int row = m0 + wm + i * 16 + lk * 4 + r;
      if (row >= p.M) continue;
#pragma unroll
      for (int j = 0; j < 4; ++j){
        int col = n0 + wn + j * 16 + lr;
        if (col >= p.N) continue;
        float v = acc[i][j][r];
        if (p.mode == 1 || p.mode == 2 || p.mode == 4) v += p.bias[col];
        if (p.mode == 2) v = 0.5f * v * (1.f + erff(v * 0.70710678118f));
        long idx = offC + (long)row * p.ldc + col;
        if (p.mode == 4) v += p.res[idx];
        if (p.mode >= 3) ((float*)p.C)[idx] = v;
        else             ((u16*)p.C)[idx] = f2bf(v);
      }
    }
  }
}

static inline void gemm(hipStream_t s, const u16* A, int lda, const u16* B, int ldb,
    void* C, int ldc, int M, int N, int K, const float* bias, const float* res,
    int mode, int batches = 1, int H = 0,
    long sAb = 0, long sAh = 0, long sBb = 0, long sBh = 0, long sCb = 0, long sCh = 0){
  GemmP p{ A, B, C, bias, res, M, N, K, lda, ldb, ldc, mode, H,
           sAb, sAh, sBb, sBh, sCb, sCh };
  dim3 g(M / 128, (N + 127) / 128, batches);
  k_gemm_bt<<<g, 256, 0, s>>>(p);
}

extern "C" void kernel_launch(void* const* d_in, const int* in_sizes, int n_in,
                              void* d_out, int out_size, void* d_ws, size_t ws_size,
                              hipStream_t stream){
  (void)in_sizes; (void)n_in; (void)out_size; (void)ws_size;
  const float* x    = (const float*)d_in[0];
  const float* Wqkv = (const float*)d_in[1];
  const float* bqkv = (const float*)d_in[2];
  const float* Wo   = (const float*)d_in[3];
  const float* bo   = (const float*)d_in[4];
  const float* W1   = (const float*)d_in[5];
  const float* b1   = (const float*)d_in[6];
  const float* W2   = (const float*)d_in[7];
  const float* b2   = (const float*)d_in[8];
  const float* ln1g = (const float*)d_in[9];
  const float* ln1b = (const float*)d_in[10];
  const float* ln2g = (const float*)d_in[11];
  const float* ln2b = (const float*)d_in[12];
  const float* lnfg = (const float*)d_in[13];
  const float* lnfb = (const float*)d_in[14];
  const float* Wlm  = (const float*)d_in[15];

  char* ws = (char*)d_ws;
  size_t off = 0;
  auto alloc = [&](size_t bytes){ void* p = ws + off; off += (bytes + 255) & ~255UL; return p; };
  float* h      = (float*)alloc((size_t)TT * NE * 4);
  u16*   a      = (u16*)  alloc((size_t)TT * NE * 2);
  u16*   qkv    = (u16*)  alloc((size_t)TT * 3 * NE * 2);
  u16*   vt     = (u16*)  alloc((size_t)NB * NH * HD * SL * 2);
  float* scores = (float*)alloc((size_t)NB * NH * SL * SL * 4);
  u16*   probs  = (u16*)  alloc((size_t)NB * NH * SL * SL * 2);
  u16*   attno  = (u16*)  alloc((size_t)TT * NE * 2);
  u16*   ffm    = (u16*)  alloc((size_t)TT * DFF * 2);
  u16*   wqkvT  = (u16*)  alloc((size_t)3 * NE * NE * 2);
  u16*   woT    = (u16*)  alloc((size_t)NE * NE * 2);
  u16*   w1T    = (u16*)  alloc((size_t)DFF * NE * 2);
  u16*   w2T    = (u16*)  alloc((size_t)NE * DFF * 2);
  u16*   wlmB   = (u16*)  alloc((size_t)NV * NE * 2);

  // h = x
  hipMemcpyAsync(h, x, (size_t)TT * NE * 4, hipMemcpyDeviceToDevice, stream);
  // Wlm fp32 -> bf16 (already [N][K] layout)
  k_cvt4<<<2048, 256, 0, stream>>>((const float4*)Wlm, (u16x4*)wlmB, (long)NV * NE / 4);

  for (int L = 0; L < NL; ++L){
    const float* wqkvL = Wqkv + (size_t)L * NE * 3 * NE;
    const float* woL   = Wo   + (size_t)L * NE * NE;
    const float* w1L   = W1   + (size_t)L * NE * DFF;
    const float* w2L   = W2   + (size_t)L * DFF * NE;
    k_transpose_cvt<<<dim3(3 * NE / 32, NE / 32), 256, 0, stream>>>(wqkvL, wqkvT, NE, 3 * NE);
    k_transpose_cvt<<<dim3(NE / 32, NE / 32),     256, 0, stream>>>(woL,   woT,   NE, NE);
    k_transpose_cvt<<<dim3(DFF / 32, NE / 32),    256, 0, stream>>>(w1L,   w1T,   NE, DFF);
    k_transpose_cvt<<<dim3(NE / 32, DFF / 32),    256, 0, stream>>>(w2L,   w2T,   DFF, NE);

    // ln1 -> a
    k_layernorm<<<TT, 256, 0, stream>>>(h, ln1g + L * NE, ln1b + L * NE, a);
    // qkv = a @ WqkvT^T + bqkv  (bf16)
    gemm(stream, a, NE, wqkvT, NE, qkv, 3 * NE, TT, 3 * NE, NE,
         bqkv + (size_t)L * 3 * NE, nullptr, 1);
    // V^T per (b,h)
    k_build_vt<<<dim3(NB * NH, SL / 32), 256, 0, stream>>>(qkv, vt);
    // scores = Q @ K^T  (batched over 24 bh)
    gemm(stream, qkv, 3 * NE, qkv + NE, 3 * NE, scores, SL, SL, SL, HD,
         nullptr, nullptr, 3, NB * NH, NH,
         (long)SL * 3 * NE, HD, (long)SL * 3 * NE, HD,
         (long)NH * SL * SL, (long)SL * SL);
    // softmax causal
    k_softmax<<<NB * NH * SL, 256, 0, stream>>>(scores, probs);
    // O = P @ V  (batched)
    gemm(stream, probs, SL, vt, SL, attno, NE, SL, HD, SL,
         nullptr, nullptr, 0, NB * NH, NH,
         (long)NH * SL * SL, (long)SL * SL, (long)NH * HD * SL, (long)HD * SL,
         (long)SL * NE, HD);
    // h += attno @ WoT^T + bo
    gemm(stream, attno, NE, woT, NE, h, NE, TT, NE, NE,
         bo + (size_t)L * NE, h, 4);
    // ln2 -> a
    k_layernorm<<<TT, 256, 0, stream>>>(h, ln2g + L * NE, ln2b + L * NE, a);
    // ffm = gelu(a @ W1T^T + b1)
    gemm(stream, a, NE, w1T, NE, ffm, DFF, TT, DFF, NE,
         b1 + (size_t)L * DFF, nullptr, 2);
    // h += ffm @ W2T^T + b2
    gemm(stream, ffm, DFF, w2T, DFF, h, NE, TT, NE, DFF,
         b2 + (size_t)L * NE, h, 4);
  }
  // final LN -> a
  k_layernorm<<<TT, 256, 0, stream>>>(h, lnfg, lnfb, a);
  // logits = a @ Wlm^T  (f32 out)
  gemm(stream, a, NE, wlmB, NE, d_out, NV, TT, NV, NE,
       nullptr, nullptr, 3);
}

// Round 2
// 4394.432 us; speedup vs baseline: 1.1309x; 1.1309x over previous
//
#include <hip/hip_runtime.h>
#include <math.h>

typedef unsigned short u16;
typedef u16 u16x8 __attribute__((ext_vector_type(8)));
typedef u16 u16x4 __attribute__((ext_vector_type(4)));
typedef short short8 __attribute__((ext_vector_type(8)));
typedef float f32x4 __attribute__((ext_vector_type(4)));

#define NE 768
#define NH 12
#define NL 12
#define NV 50257
#define NVP 50304   // NV padded to 128 multiple for unguarded B staging
#define HD 64
#define DFF 3072
#define NB 2
#define SL 1024
#define TT 2048   // NB*SL tokens

static __device__ __forceinline__ u16 f2bf(float f){
  unsigned int x; __builtin_memcpy(&x, &f, 4);
  x = (x + 0x7FFFu + ((x >> 16) & 1u)) >> 16;
  return (u16)x;
}

typedef const __attribute__((address_space(1))) unsigned int* gas1_t;
typedef __attribute__((address_space(3))) unsigned int* las3_t;
static __device__ __forceinline__ void gload16(const u16* g, u16* l){
  __builtin_amdgcn_global_load_lds((gas1_t)(const void*)g, (las3_t)(void*)l, 16, 0, 0);
}

// ---------------- fp32 -> bf16 convert (vectorized) ----------------
__global__ void k_cvt4(const float4* __restrict__ in, u16x4* __restrict__ out, long n4){
  long i = (long)blockIdx.x * blockDim.x + threadIdx.x;
  long st = (long)gridDim.x * blockDim.x;
  for (; i < n4; i += st){
    float4 v = in[i];
    u16x4 o = { f2bf(v.x), f2bf(v.y), f2bf(v.z), f2bf(v.w) };
    out[i] = o;
  }
}

// ------------- fp32 [K][N] -> bf16 [N][K] transpose-convert -------------
__global__ __launch_bounds__(256) void k_transpose_cvt(const float* __restrict__ in,
    u16* __restrict__ out, int K, int N){
  __shared__ u16 tile[32][33];
  int n0 = blockIdx.x * 32, k0 = blockIdx.y * 32;
#pragma unroll
  for (int i = 0; i < 4; ++i){
    int e = threadIdx.x + i * 256;
    int r = e >> 5, c = e & 31;          // r: k, c: n
    int k = k0 + r, n = n0 + c;
    float v = (k < K && n < N) ? in[(long)k * N + n] : 0.f;
    tile[r][c] = f2bf(v);
  }
  __syncthreads();
#pragma unroll
  for (int i = 0; i < 4; ++i){
    int e = threadIdx.x + i * 256;
    int r = e >> 5, c = e & 31;          // r: n, c: k
    int n = n0 + r, k = k0 + c;
    if (n < N && k < K) out[(long)n * K + k] = tile[c][r];
  }
}

// ---------------- LayerNorm: f32 [TT][768] -> bf16 ----------------
__global__ __launch_bounds__(256) void k_layernorm(const float* __restrict__ x,
    const float* __restrict__ g, const float* __restrict__ b, u16* __restrict__ out){
  int row = blockIdx.x;
  const float* xr = x + (long)row * NE;
  int t = threadIdx.x;
  float v[3];
  v[0] = xr[t]; v[1] = xr[t + 256]; v[2] = xr[t + 512];
  float s = v[0] + v[1] + v[2];
  float sq = v[0]*v[0] + v[1]*v[1] + v[2]*v[2];
  __shared__ float red[8];
#pragma unroll
  for (int o = 32; o; o >>= 1){ s += __shfl_xor(s, o); sq += __shfl_xor(sq, o); }
  int wid = t >> 6, lane = t & 63;
  if (!lane){ red[wid] = s; red[4 + wid] = sq; }
  __syncthreads();
  s  = red[0] + red[1] + red[2] + red[3];
  sq = red[4] + red[5] + red[6] + red[7];
  float mean = s * (1.f / NE);
  float var  = sq * (1.f / NE) - mean * mean;
  float rs = rsqrtf(var + 1e-5f);
  u16* orow = out + (long)row * NE;
#pragma unroll
  for (int i = 0; i < 3; ++i){
    int c = t + i * 256;
    orow[c] = f2bf((v[i] - mean) * rs * g[c] + b[c]);
  }
}

// -------- build V^T: qkv bf16 -> vt[bh][d][kk] --------
__global__ __launch_bounds__(256) void k_build_vt(const u16* __restrict__ qkv,
    u16* __restrict__ vt){
  int z = blockIdx.x;                    // b*12 + h
  int b = z / NH, h = z % NH;
  int kk0 = blockIdx.y * 32;
  __shared__ u16 tile[32][66];
  const u16* src = qkv + ((long)(b * SL + kk0)) * (3 * NE) + 2 * NE + h * HD;
#pragma unroll
  for (int i = 0; i < 8; ++i){
    int e = threadIdx.x + i * 256;
    int kk = e >> 6, d = e & 63;
    tile[kk][d] = src[(long)kk * (3 * NE) + d];
  }
  __syncthreads();
  u16* dst = vt + (long)z * HD * SL + kk0;
#pragma unroll
  for (int i = 0; i < 8; ++i){
    int e = threadIdx.x + i * 256;
    int d = e >> 5, kk = e & 31;
    dst[(long)d * SL + kk] = tile[kk][d];
  }
}

// -------- causal softmax: scores f32 [24*SL][SL] -> probs bf16 --------
__global__ __launch_bounds__(256) void k_softmax(const float* __restrict__ sc,
    u16* __restrict__ pr){
  long rowbase = (long)blockIdx.x * SL;
  int q = blockIdx.x & (SL - 1);
  int t = threadIdx.x, wid = t >> 6, lane = t & 63;
  __shared__ float red[4];
  float vals[4];
  float mx = -1e30f;
#pragma unroll
  for (int i = 0; i < 4; ++i){
    int c = t + i * 256;
    float v = sc[rowbase + c] * 0.125f;
    if (c > q) v = -1e30f;
    vals[i] = v;
    mx = fmaxf(mx, v);
  }
#pragma unroll
  for (int o = 32; o; o >>= 1) mx = fmaxf(mx, __shfl_xor(mx, o));
  if (!lane) red[wid] = mx;
  __syncthreads();
  mx = fmaxf(fmaxf(red[0], red[1]), fmaxf(red[2], red[3]));
  __syncthreads();
  float sum = 0.f;
#pragma unroll
  for (int i = 0; i < 4; ++i){
    float e = __expf(vals[i] - mx);
    vals[i] = e; sum += e;
  }
#pragma unroll
  for (int o = 32; o; o >>= 1) sum += __shfl_xor(sum, o);
  if (!lane) red[wid] = sum;
  __syncthreads();
  sum = red[0] + red[1] + red[2] + red[3];
  float inv = 1.f / sum;
#pragma unroll
  for (int i = 0; i < 4; ++i){
    int c = t + i * 256;
    pr[rowbase + c] = f2bf(vals[i] * inv);
  }
}

// ---------------- generic bf16 MFMA GEMM, B^T layout (m97 structure) ----------------
// C[M,N] = A[M,K] * B^T[N,K]  (+bias)(+res)(gelu), optional batch via grid.z
// modes: 0 bf16 raw, 1 bf16 +bias, 2 bf16 +bias +gelu(erf), 3 f32 raw, 4 f32 +bias +res
// causal: 0 none, 1 skip blocks with n0 > m0+127 (QK^T), 2 cap K at m0+128 (PV)
struct GemmP {
  const u16* A; const u16* B; void* C;
  const float* bias; const float* res;
  int M, N, K, lda, ldb, ldc, mode, H, causal;
  long sAb, sAh, sBb, sBh, sCb, sCh;
};

__global__ __launch_bounds__(256) void k_gemm_bt(GemmP p){
  __shared__ u16 As[128 * 32];
  __shared__ u16 Bs[128 * 32];
  const int m0 = blockIdx.x * 128, n0 = blockIdx.y * 128;
  if (p.causal == 1 && n0 > m0 + 127) return;   // fully-masked score block
  int Keff = p.K;
  if (p.causal == 2) Keff = min(p.K, m0 + 128); // probs are 0 beyond the diagonal
  long offA = 0, offB = 0, offC = 0;
  if (p.H){
    int z = blockIdx.z, zb = z / p.H, zh = z % p.H;
    offA = (long)zb * p.sAb + (long)zh * p.sAh;
    offB = (long)zb * p.sBb + (long)zh * p.sBh;
    offC = (long)zb * p.sCb + (long)zh * p.sCh;
  }
  const u16* A = p.A + offA;
  const u16* B = p.B + offB;
  const int t = threadIdx.x, lane = t & 63, wid = t >> 6;
  const int wm = (wid >> 1) * 64, wn = (wid & 1) * 64;
  const int lr = lane & 15, lk = lane >> 4;
  // staging geometry: wave wid, call j in {0,1}: 1024B chunk = 16 rows of 64B
  // lane covers row = (wid*2+j)*16 + (lane>>2), 16B segment seg = lane&3
  const int srow0 = wid * 32 + (lane >> 2);   // j=0 row
  const int sseg  = (lane & 3) * 8;           // u16 offset within row
  f32x4 acc[4][4] = {};
  for (int k0 = 0; k0 < Keff; k0 += 32){
    const u16* Ab = A + (long)(m0 + srow0) * p.lda + k0 + sseg;
    const u16* Bb = B + (long)(n0 + srow0) * p.ldb + k0 + sseg;
    gload16(Ab, As + (wid * 2 + 0) * 512);
    gload16(Ab + 16 * p.lda, As + (wid * 2 + 1) * 512);
    gload16(Bb, Bs + (wid * 2 + 0) * 512);
    gload16(Bb + 16 * p.ldb, Bs + (wid * 2 + 1) * 512);
    __syncthreads();
    short8 af[4], bfr[4];
#pragma unroll
    for (int i = 0; i < 4; ++i) af[i]  = *(const short8*)&As[(wm + i * 16 + lr) * 32 + lk * 8];
#pragma unroll
    for (int j = 0; j < 4; ++j) bfr[j] = *(const short8*)&Bs[(wn + j * 16 + lr) * 32 + lk * 8];
#pragma unroll
    for (int i = 0; i < 4; ++i)
#pragma unroll
      for (int j = 0; j < 4; ++j)
        acc[i][j] = __builtin_amdgcn_mfma_f32_16x16x32_bf16(af[i], bfr[j], acc[i][j], 0, 0, 0);
    __syncthreads();
  }
#pragma unroll
  for (int i = 0; i < 4; ++i){
#pragma unroll
    for (int r = 0; r < 4; ++r){
      int row = m0 + wm + i * 16 + lk * 4 + r;
      if (row >= p.M) continue;
#pragma unroll
      for (int j = 0; j < 4; ++j){
        int col = n0 + wn + j * 16 + lr;
        if (col >= p.N) continue;
        float v = acc[i][j][r];
        if (p.mode == 1 || p.mode == 2 || p.mode == 4) v += p.bias[col];
        if (p.mode == 2) v = 0.5f * v * (1.f + erff(v * 0.70710678118f));
        long idx = offC + (long)row * p.ldc + col;
        if (p.mode == 4) v += p.res[idx];
        if (p.mode >= 3) ((float*)p.C)[idx] = v;
        else             ((u16*)p.C)[idx] = f2bf(v);
      }
    }
  }
}

static inline void gemm(hipStream_t s, const u16* A, int lda, const u16* B, int ldb,
    void* C, int ldc, int M, int N, int K, const float* bias, const float* res,
    int mode, int causal = 0, int batches = 1, int H = 0,
    long sAb = 0, long sAh = 0, long sBb = 0, long sBh = 0, long sCb = 0, long sCh = 0){
  GemmP p{ A, B, C, bias, res, M, N, K, lda, ldb, ldc, mode, H, causal,
           sAb, sAh, sBb, sBh, sCb, sCh };
  dim3 g(M / 128, (N + 127) / 128, batches);
  k_gemm_bt<<<g, 256, 0, s>>>(p);
}

extern "C" void kernel_launch(void* const* d_in, const int* in_sizes, int n_in,
                              void* d_out, int out_size, void* d_ws, size_t ws_size,
                              hipStream_t stream){
  (void)in_sizes; (void)n_in; (void)out_size; (void)ws_size;
  const float* x    = (const float*)d_in[0];
  const float* Wqkv = (const float*)d_in[1];
  const float* bqkv = (const float*)d_in[2];
  const float* Wo   = (const float*)d_in[3];
  const float* bo   = (const float*)d_in[4];
  const float* W1   = (const float*)d_in[5];
  const float* b1   = (const float*)d_in[6];
  const float* W2   = (const float*)d_in[7];
  const float* b2   = (const float*)d_in[8];
  const float* ln1g = (const float*)d_in[9];
  const float* ln1b = (const float*)d_in[10];
  const float* ln2g = (const float*)d_in[11];
  const float* ln2b = (const float*)d_in[12];
  const float* lnfg = (const float*)d_in[13];
  const float* lnfb = (const float*)d_in[14];
  const float* Wlm  = (const float*)d_in[15];

  char* ws = (char*)d_ws;
  size_t off = 0;
  auto alloc = [&](size_t bytes){ void* p = ws + off; off += (bytes + 255) & ~255UL; return p; };
  float* h      = (float*)alloc((size_t)TT * NE * 4);
  u16*   a      = (u16*)  alloc((size_t)TT * NE * 2);
  u16*   qkv    = (u16*)  alloc((size_t)TT * 3 * NE * 2);
  u16*   vt     = (u16*)  alloc((size_t)NB * NH * HD * SL * 2);
  float* scores = (float*)alloc((size_t)NB * NH * SL * SL * 4);
  u16*   probs  = (u16*)  alloc((size_t)NB * NH * SL * SL * 2);
  u16*   attno  = (u16*)  alloc((size_t)TT * NE * 2);
  u16*   ffm    = (u16*)  alloc((size_t)TT * DFF * 2);
  u16*   wqkvT  = (u16*)  alloc((size_t)3 * NE * NE * 2);
  u16*   woT    = (u16*)  alloc((size_t)NE * NE * 2);
  u16*   w1T    = (u16*)  alloc((size_t)DFF * NE * 2);
  u16*   w2T    = (u16*)  alloc((size_t)NE * DFF * 2);
  u16*   wlmB   = (u16*)  alloc((size_t)NVP * NE * 2);

  // h = x
  hipMemcpyAsync(h, x, (size_t)TT * NE * 4, hipMemcpyDeviceToDevice, stream);
  // Wlm fp32 -> bf16 (already [N][K] layout); zero the 47 pad rows
  k_cvt4<<<2048, 256, 0, stream>>>((const float4*)Wlm, (u16x4*)wlmB, (long)NV * NE / 4);
  hipMemsetAsync(wlmB + (size_t)NV * NE, 0, (size_t)(NVP - NV) * NE * 2, stream);

  for (int L = 0; L < NL; ++L){
    const float* wqkvL = Wqkv + (size_t)L * NE * 3 * NE;
    const float* woL   = Wo   + (size_t)L * NE * NE;
    const float* w1L   = W1   + (size_t)L * NE * DFF;
    const float* w2L   = W2   + (size_t)L * DFF * NE;
    k_transpose_cvt<<<dim3(3 * NE / 32, NE / 32), 256, 0, stream>>>(wqkvL, wqkvT, NE, 3 * NE);
    k_transpose_cvt<<<dim3(NE / 32, NE / 32),     256, 0, stream>>>(woL,   woT,   NE, NE);
    k_transpose_cvt<<<dim3(DFF / 32, NE / 32),    256, 0, stream>>>(w1L,   w1T,   NE, DFF);
    k_transpose_cvt<<<dim3(NE / 32, DFF / 32),    256, 0, stream>>>(w2L,   w2T,   DFF, NE);

    // ln1 -> a
    k_layernorm<<<TT, 256, 0, stream>>>(h, ln1g + L * NE, ln1b + L * NE, a);
    // qkv = a @ WqkvT^T + bqkv  (bf16)
    gemm(stream, a, NE, wqkvT, NE, qkv, 3 * NE, TT, 3 * NE, NE,
         bqkv + (size_t)L * 3 * NE, nullptr, 1);
    // V^T per (b,h)
    k_build_vt<<<dim3(NB * NH, SL / 32), 256, 0, stream>>>(qkv, vt);
    // scores = Q @ K^T  (batched over 24 bh), causal block-skip
    gemm(stream, qkv, 3 * NE, qkv + NE, 3 * NE, scores, SL, SL, SL, HD,
         nullptr, nullptr, 3, 1, NB * NH, NH,
         (long)SL * 3 * NE, HD, (long)SL * 3 * NE, HD,
         (long)NH * SL * SL, (long)SL * SL);
    // softmax causal
    k_softmax<<<NB * NH * SL, 256, 0, stream>>>(scores, probs);
    // O = P @ V  (batched), K capped at diagonal
    gemm(stream, probs, SL, vt, SL, attno, NE, SL, HD, SL,
         nullptr, nullptr, 0, 2, NB * NH, NH,
         (long)NH * SL * SL, (long)SL * SL, (long)NH * HD * SL, (long)HD * SL,
         (long)SL * NE, HD);
    // h += attno @ WoT^T + bo
    gemm(stream, attno, NE, woT, NE, h, NE, TT, NE, NE,
         bo + (size_t)L * NE, h, 4);
    // ln2 -> a
    k_layernorm<<<TT, 256, 0, stream>>>(h, ln2g + L * NE, ln2b + L * NE, a);
    // ffm = gelu(a @ W1T^T + b1)
    gemm(stream, a, NE, w1T, NE, ffm, DFF, TT, DFF, NE,
         b1 + (size_t)L * DFF, nullptr, 2);
    // h += ffm @ W2T^T + b2
    gemm(stream, ffm, DFF, w2T, DFF, h, NE, TT, NE, DFF,
         b2 + (size_t)L * NE, h, 4);
  }
  // final LN -> a
  k_layernorm<<<TT, 256, 0, stream>>>(h, lnfg, lnfb, a);
  // logits = a @ Wlm^T  (f32 out)
  gemm(stream, a, NE, wlmB, NE, d_out, NV, TT, NV, NE,
       nullptr, nullptr, 3);
}